// Round 2
// baseline (367.668 us; speedup 1.0000x reference)
//
#include <hip/hip_runtime.h>
#include <cstdint>
#include <cstddef>

typedef unsigned short u16;
typedef short bf16x8 __attribute__((ext_vector_type(8)));
typedef float f32x4 __attribute__((ext_vector_type(4)));

#define NBATCH 2
#define NS 2048
#define NDIM 1024
#define NH 16
#define NHD 64

__device__ __forceinline__ u16 f2b(float f) {
  union { float f; unsigned u; } x; x.f = f;
  return (u16)((x.u + 0x7fffu + ((x.u >> 16) & 1u)) >> 16);
}

// ---------------- f32 -> bf16 conversion (vectorized) ----------------
__global__ void cvt_bf16(const float* __restrict__ s, u16* __restrict__ d, int n) {
  int i = (blockIdx.x * blockDim.x + threadIdx.x) * 4;
  if (i >= n) return;
  float4 v = *reinterpret_cast<const float4*>(s + i);
  ushort4 o;
  o.x = f2b(v.x); o.y = f2b(v.y); o.z = f2b(v.z); o.w = f2b(v.w);
  *reinterpret_cast<ushort4*>(d + i) = o;
}

// ---------------- GEMM: C[m,n] = sum_k A[m,k] * Bt[n,k] ----------------
// A: (M=4096, K=1024) bf16 row-major. Bt: (N=1024, K=1024) bf16 row-major.
// MODE 0: store f32 to Cf (row-major M x 1024)
// MODE 1: RoPE epilogue, store bf16 to Cb in (b,h,s,d) layout  (q or k)
// MODE 2: plain bf16 store to Cb in (b,h,s,d) layout            (v)
template<int MODE>
__global__ __launch_bounds__(256, 2)
void gemm_bt(const u16* __restrict__ A, const u16* __restrict__ Bt,
             float* __restrict__ Cf, u16* __restrict__ Cb,
             const float* __restrict__ cosp, const float* __restrict__ sinp) {
  __shared__ __align__(16) u16 sA[128 * 32];
  __shared__ __align__(16) u16 sB[128 * 32];
  const int lane = threadIdx.x & 63;
  const int wid  = threadIdx.x >> 6;
  const int wm = wid >> 1, wn = wid & 1;
  const int tm = blockIdx.x * 128, tn = blockIdx.y * 128;
  const int fr = lane & 15, fq = lane >> 4;
  const int sr = lane >> 2, sc = lane & 3;

  const f32x4 fzero = {0.f, 0.f, 0.f, 0.f};
  f32x4 acc[4][4];
#pragma unroll
  for (int i = 0; i < 4; ++i)
#pragma unroll
    for (int j = 0; j < 4; ++j) acc[i][j] = fzero;

  // staging: each wave stages 32 rows of A and 32 rows of Bt per K-step.
  // global_load_lds: LDS dest = wave-uniform base + lane*16B (linear), so
  // global src lane order must match [row][col] row-major LDS layout.
  const u16* gA0 = A  + (size_t)(tm + wid * 32 + sr) * NDIM + sc * 8;
  const u16* gB0 = Bt + (size_t)(tn + wid * 32 + sr) * NDIM + sc * 8;
  u16* lA = &sA[wid * 32 * 32];
  u16* lB = &sB[wid * 32 * 32];

  for (int k0 = 0; k0 < NDIM; k0 += 32) {
    __builtin_amdgcn_global_load_lds((const __attribute__((address_space(1))) unsigned*)(gA0 + k0),
                                     (__attribute__((address_space(3))) unsigned*)lA, 16, 0, 0);
    __builtin_amdgcn_global_load_lds((const __attribute__((address_space(1))) unsigned*)(gA0 + k0 + 16 * NDIM),
                                     (__attribute__((address_space(3))) unsigned*)(lA + 16 * 32), 16, 0, 0);
    __builtin_amdgcn_global_load_lds((const __attribute__((address_space(1))) unsigned*)(gB0 + k0),
                                     (__attribute__((address_space(3))) unsigned*)lB, 16, 0, 0);
    __builtin_amdgcn_global_load_lds((const __attribute__((address_space(1))) unsigned*)(gB0 + k0 + 16 * NDIM),
                                     (__attribute__((address_space(3))) unsigned*)(lB + 16 * 32), 16, 0, 0);
    __syncthreads();

    bf16x8 af[4], bff[4];
#pragma unroll
    for (int i = 0; i < 4; ++i)
      af[i] = *reinterpret_cast<const bf16x8*>(&sA[(wm * 64 + i * 16 + fr) * 32 + fq * 8]);
#pragma unroll
    for (int i = 0; i < 4; ++i)
      bff[i] = *reinterpret_cast<const bf16x8*>(&sB[(wn * 64 + i * 16 + fr) * 32 + fq * 8]);
#pragma unroll
    for (int mi = 0; mi < 4; ++mi)
#pragma unroll
      for (int ni = 0; ni < 4; ++ni)
        acc[mi][ni] = __builtin_amdgcn_mfma_f32_16x16x32_bf16(af[mi], bff[ni], acc[mi][ni], 0, 0, 0);
    __syncthreads();
  }

  // epilogue: C/D layout col = lane&15, row = (lane>>4)*4 + reg  [m89-verified]
#pragma unroll
  for (int mi = 0; mi < 4; ++mi) {
#pragma unroll
    for (int ni = 0; ni < 4; ++ni) {
#pragma unroll
      for (int r = 0; r < 4; ++r) {
        const int row = tm + wm * 64 + mi * 16 + fq * 4 + r;
        const int col = tn + wn * 64 + ni * 16 + fr;
        float val = acc[mi][ni][r];
        if (MODE == 0) {
          Cf[(size_t)row * NDIM + col] = val;
        } else {
          const int b = row >> 11, s = row & (NS - 1);
          const int h = col >> 6,  d = col & 63;
          if (MODE == 1) {
            // RoPE: pair (2i, 2i+1) within head; partner col = col^1 lives in lane^1
            const int fi = d >> 1;
            const float c  = cosp[s * 32 + fi];
            const float sn = sinp[s * 32 + fi];
            const float partner = __shfl_xor(val, 1);
            val = (d & 1) ? (partner * sn + val * c) : (val * c - partner * sn);
          }
          Cb[((size_t)(b * NH + h) * NS + s) * NHD + d] = f2b(val);
        }
      }
    }
  }
}

// ---------------- causal flash attention ----------------
// Q,K,V: bf16 (b,h,s,d). O: bf16 (b,s,h*64+d) = (4096,1024) row-major.
// grid = (B*H) * (S/64); block = 256 (4 waves); wave w owns 16 q-rows.
__global__ __launch_bounds__(256, 2)
void attn_fwd(const u16* __restrict__ Q, const u16* __restrict__ K,
              const u16* __restrict__ V, u16* __restrict__ O) {
  __shared__ __align__(16) u16 p_lds[4][16 * 32];
  const int lane = threadIdx.x & 63;
  const int w = threadIdx.x >> 6;
  const int bh = blockIdx.x >> 5;
  const int qt = blockIdx.x & 31;
  const int q0 = qt * 64 + w * 16;
  const int fr = lane & 15, fq = lane >> 4;
  const size_t base = (size_t)bh * NS * NHD;

  const f32x4 fzero = {0.f, 0.f, 0.f, 0.f};
  // Q fragments (A-operand: row = lane&15, k = (lane>>4)*8 + j (+32))
  bf16x8 aq0 = *reinterpret_cast<const bf16x8*>(&Q[base + (size_t)(q0 + fr) * NHD + fq * 8]);
  bf16x8 aq1 = *reinterpret_cast<const bf16x8*>(&Q[base + (size_t)(q0 + fr) * NHD + 32 + fq * 8]);

  float m[4], lsum[4];
  f32x4 o[4];
#pragma unroll
  for (int r = 0; r < 4; ++r) { m[r] = -1e30f; lsum[r] = 0.f; }
#pragma unroll
  for (int nb = 0; nb < 4; ++nb) o[nb] = fzero;

  const int nkt = (q0 + 16 + 31) >> 5;  // key tiles of 32, causal bound
  for (int kt = 0; kt < nkt; ++kt) {
    const int key0 = kt * 32;
    float ps[2][4];
    // S = Q K^T  (B-operand: col = key = lane&15, k = d contiguous)
#pragma unroll
    for (int h = 0; h < 2; ++h) {
      const u16* kp = &K[base + (size_t)(key0 + h * 16 + fr) * NHD + fq * 8];
      bf16x8 kb0 = *reinterpret_cast<const bf16x8*>(kp);
      bf16x8 kb1 = *reinterpret_cast<const bf16x8*>(kp + 32);
      f32x4 sf = fzero;
      sf = __builtin_amdgcn_mfma_f32_16x16x32_bf16(aq0, kb0, sf, 0, 0, 0);
      sf = __builtin_amdgcn_mfma_f32_16x16x32_bf16(aq1, kb1, sf, 0, 0, 0);
      const int key = key0 + h * 16 + fr;
#pragma unroll
      for (int r = 0; r < 4; ++r)
        ps[h][r] = (key > q0 + fq * 4 + r) ? -1e30f : sf[r] * 0.125f;
    }
    // online softmax: per-lane rows = q0 + fq*4 + r; reduce across 16 key-lanes
#pragma unroll
    for (int r = 0; r < 4; ++r) {
      float rm = fmaxf(ps[0][r], ps[1][r]);
#pragma unroll
      for (int off = 1; off < 16; off <<= 1) rm = fmaxf(rm, __shfl_xor(rm, off));
      const float mn = fmaxf(m[r], rm);
      const float al = __expf(m[r] - mn);
      ps[0][r] = __expf(ps[0][r] - mn);
      ps[1][r] = __expf(ps[1][r] - mn);
      float rs = ps[0][r] + ps[1][r];
#pragma unroll
      for (int off = 1; off < 16; off <<= 1) rs += __shfl_xor(rs, off);
      lsum[r] = lsum[r] * al + rs;
      m[r] = mn;
#pragma unroll
      for (int nb = 0; nb < 4; ++nb) o[nb][r] *= al;
    }
    // P (C-layout) -> LDS -> reload as A-operand fragment. Wave-local:
    // DS ops are in-order within a wave; no __syncthreads (divergent loops).
#pragma unroll
    for (int h = 0; h < 2; ++h)
#pragma unroll
      for (int r = 0; r < 4; ++r)
        p_lds[w][(fq * 4 + r) * 32 + h * 16 + fr] = f2b(ps[h][r]);
    __builtin_amdgcn_wave_barrier();
    asm volatile("s_waitcnt lgkmcnt(0)" ::: "memory");
    bf16x8 ap = *reinterpret_cast<const bf16x8*>(&p_lds[w][fr * 32 + fq * 8]);
    __builtin_amdgcn_wave_barrier();
    // O += P V   (B-operand: col = d, k = key; V is (key, d) -> strided scalar loads)
#pragma unroll
    for (int nb = 0; nb < 4; ++nb) {
      bf16x8 bv;
#pragma unroll
      for (int j = 0; j < 8; ++j)
        bv[j] = (short)V[base + (size_t)(key0 + fq * 8 + j) * NHD + nb * 16 + fr];
      o[nb] = __builtin_amdgcn_mfma_f32_16x16x32_bf16(ap, bv, o[nb], 0, 0, 0);
    }
  }
  const int b = bh >> 4, h = bh & 15;
#pragma unroll
  for (int nb = 0; nb < 4; ++nb)
#pragma unroll
    for (int r = 0; r < 4; ++r) {
      const int qrow = q0 + fq * 4 + r;
      const int d = nb * 16 + fr;
      O[((size_t)(b * NS + qrow)) * NDIM + h * NHD + d] = f2b(o[nb][r] / lsum[r]);
    }
}

// ---------------- launch ----------------
extern "C" void kernel_launch(void* const* d_in, const int* in_sizes, int n_in,
                              void* d_out, int out_size, void* d_ws, size_t ws_size,
                              hipStream_t stream) {
  const float* x  = (const float*)d_in[0];
  const float* wq = (const float*)d_in[1];
  const float* wk = (const float*)d_in[2];
  const float* wv = (const float*)d_in[3];
  const float* wo = (const float*)d_in[4];
  const float* fc = (const float*)d_in[5];
  const float* fs = (const float*)d_in[6];
  // d_in[7] = mask: implemented as causal predicate, not read.

  // workspace layout (u16 elements): 48 MB total
  u16* xb  = (u16*)d_ws;            // x bf16        (4096x1024)
  u16* wqb = xb  + 4194304;
  u16* wkb = wqb + 1048576;
  u16* wvb = wkb + 1048576;
  u16* wob = wvb + 1048576;
  u16* qw  = wob + 1048576;         // q (b,h,s,d)
  u16* kw  = qw  + 4194304;         // k (b,h,s,d)
  u16* vw  = kw  + 4194304;         // v (b,h,s,d)
  u16* aw  = vw  + 4194304;         // attn out (b,s,dim)

  cvt_bf16<<<4096, 256, 0, stream>>>(x,  xb,  4194304);
  cvt_bf16<<<1024, 256, 0, stream>>>(wq, wqb, 1048576);
  cvt_bf16<<<1024, 256, 0, stream>>>(wk, wkb, 1048576);
  cvt_bf16<<<1024, 256, 0, stream>>>(wv, wvb, 1048576);
  cvt_bf16<<<1024, 256, 0, stream>>>(wo, wob, 1048576);

  dim3 g(32, 8);  // M/128 x N/128
  gemm_bt<1><<<g, 256, 0, stream>>>(xb, wqb, nullptr, qw, fc, fs);
  gemm_bt<1><<<g, 256, 0, stream>>>(xb, wkb, nullptr, kw, fc, fs);
  gemm_bt<2><<<g, 256, 0, stream>>>(xb, wvb, nullptr, vw, nullptr, nullptr);

  attn_fwd<<<NBATCH * NH * (NS / 64), 256, 0, stream>>>(qw, kw, vw, aw);

  gemm_bt<0><<<g, 256, 0, stream>>>(aw, wob, (float*)d_out, nullptr, nullptr, nullptr);
}